// Round 9
// baseline (120.817 us; speedup 1.0000x reference)
//
#include <hip/hip_runtime.h>

#define NDOF 7
#define NPARK 5                     // links 0..4 parked in LDS; 5,6 fused in regs
#define BLK 128                     // threads per block (2 waves)
#define RPB 256                     // rows per block (2 rows per thread: A, B)
#define CST_STRIDE 24               // floats per dof block (= 6 float4)
#define CST_TOT (NDOF * CST_STRIDE) // 168
#define SLOTS 8                     // per-link parked f32x2: fl(3) fa(3) s c
#define SF_V2 (NPARK * SLOTS * BLK) // 5*8*128 f32x2 = 40960 B

// ---------- packed pair type: lane .x = row A, lane .y = row B ----------
// <2 x float> IR -> v_pk_fma_f32/v_pk_add_f32/v_pk_mul_f32 on gfx950:
// one VALU instruction per 2-row operation (r8: first change to break the
// VALU-issue floor, total 130->118 us).
typedef float f32x2 __attribute__((ext_vector_type(2)));

__device__ __forceinline__ f32x2 splat(float v) { f32x2 r; r.x = v; r.y = v; return r; }

struct PV3 { f32x2 x, y, z; };
__device__ __forceinline__ PV3 operator+(PV3 a, PV3 b) { return {a.x + b.x, a.y + b.y, a.z + b.z}; }
__device__ __forceinline__ PV3 operator-(PV3 a, PV3 b) { return {a.x - b.x, a.y - b.y, a.z - b.z}; }
__device__ __forceinline__ PV3 operator*(f32x2 s, PV3 a) { return {s * a.x, s * a.y, s * a.z}; }
__device__ __forceinline__ PV3 cross(PV3 a, PV3 b) {
    return {a.y * b.z - a.z * b.y, a.z * b.x - a.x * b.z, a.x * b.y - a.y * b.x};
}
__device__ __forceinline__ f32x2 dot(PV3 a, PV3 b) { return a.x * b.x + a.y * b.y + a.z * b.z; }
__device__ __forceinline__ PV3 uv(float x, float y, float z) { return {splat(x), splat(y), splat(z)}; }

// AX: 0 = +z, 1 = +y, 2 = -y   (joint_axes is a literal in the reference)
template <int AX>
__device__ __forceinline__ void make_R(PV3 Fc0, PV3 Fc1, PV3 Fc2, f32x2 s, f32x2 c,
                                       PV3& R0, PV3& R1, PV3& R2) {
    if (AX == 0) {          // Rq_z cols: (c,s,0), (-s,c,0), (0,0,1)
        R0 = c * Fc0 + s * Fc1;
        R1 = c * Fc1 - s * Fc0;
        R2 = Fc2;
    } else if (AX == 1) {   // Rq_y cols: (c,0,-s), (0,1,0), (s,0,c)
        R0 = c * Fc0 - s * Fc2;
        R1 = Fc1;
        R2 = s * Fc0 + c * Fc2;
    } else {                // Rq_-y cols: (c,0,s), (0,1,0), (-s,0,c)
        R0 = c * Fc0 + s * Fc2;
        R1 = Fc1;
        R2 = c * Fc2 - s * Fc0;
    }
}

// fwd: both rows in one packed pass; constants wave-uniform (broadcast).
template <int AX>
__device__ __forceinline__ void fwd_step(float4 A0, float4 A1, float4 A2, float4 A3,
                                         float4 A4, float4 A5, f32x2 s, f32x2 c,
                                         f32x2 qd, f32x2 qdd, PV3& vl, PV3& va, PV3& al,
                                         PV3& aa, PV3& fl, PV3& fa) {
    const PV3 Fc0 = uv(A0.x, A0.y, A0.z);
    const PV3 Fc1 = uv(A0.w, A1.x, A1.y);
    const PV3 Fc2 = uv(A1.z, A1.w, A2.x);
    const PV3 p = uv(A2.y, A2.z, A2.w);
    const f32x2 I00 = splat(A3.x), I01 = splat(A3.y), I02 = splat(A3.z);
    const f32x2 I11 = splat(A3.w), I12 = splat(A4.x), I22 = splat(A4.y);
    const f32x2 m = splat(A4.z);
    const PV3 mc = uv(A4.w, A5.x, A5.y);

    PV3 R0, R1, R2;
    make_R<AX>(Fc0, Fc1, Fc2, s, c, R0, R1, R2);

    // Rt(vl) + cross(-Rt p, Rt va) == Rt(vl + va x p)
    PV3 w1 = vl + cross(va, p);
    PV3 w2 = al + cross(aa, p);
    PV3 nvl{dot(R0, w1), dot(R1, w1), dot(R2, w1)};
    PV3 nva{dot(R0, va), dot(R1, va), dot(R2, va)};
    PV3 nal{dot(R0, w2), dot(R1, w2), dot(R2, w2)};
    PV3 naa{dot(R0, aa), dot(R1, aa), dot(R2, aa)};

    if (AX == 0) {          // jv=(0,0,qd): cross(v,jv)=(v.y*qd,-v.x*qd,0)
        va = {nva.x, nva.y, nva.z + qd};
        aa = {naa.x + va.y * qd, naa.y - va.x * qd, naa.z + qdd};
        vl = nvl;
        al = {nal.x + vl.y * qd, nal.y - vl.x * qd, nal.z};
    } else if (AX == 1) {   // jv=(0,qd,0): cross(v,jv)=(-v.z*qd,0,v.x*qd)
        va = {nva.x, nva.y + qd, nva.z};
        aa = {naa.x - va.z * qd, naa.y + qdd, naa.z + va.x * qd};
        vl = nvl;
        al = {nal.x - vl.z * qd, nal.y, nal.z + vl.x * qd};
    } else {                // jv=(0,-qd,0): cross(v,jv)=(v.z*qd,0,-v.x*qd)
        va = {nva.x, nva.y - qd, nva.z};
        aa = {naa.x + va.z * qd, naa.y - qdd, naa.z - va.x * qd};
        vl = nvl;
        al = {nal.x + vl.z * qd, nal.y, nal.z - vl.x * qd};
    }

    PV3 Ial = m * al + cross(aa, mc);
    PV3 Iaa = PV3{I00 * aa.x + I01 * aa.y + I02 * aa.z,
                  I01 * aa.x + I11 * aa.y + I12 * aa.z,
                  I02 * aa.x + I12 * aa.y + I22 * aa.z} + cross(mc, al);
    PV3 Ivl = m * vl + cross(va, mc);
    PV3 Iva = PV3{I00 * va.x + I01 * va.y + I02 * va.z,
                  I01 * va.x + I11 * va.y + I12 * va.z,
                  I02 * va.x + I12 * va.y + I22 * va.z} + cross(mc, vl);
    fl = Ial + cross(va, Ivl);
    fa = Iaa + cross(va, Iva) + cross(vl, Ivl);
}

// bwd: both rows packed; updates carry, returns packed tau.
template <int AX>
__device__ __forceinline__ f32x2 bwd_core(float4 A0, float4 A1, float4 A2,
                                          f32x2 s, f32x2 c,
                                          PV3 fl, PV3 fa, PV3& cl, PV3& ca) {
    const PV3 Fc0 = uv(A0.x, A0.y, A0.z);
    const PV3 Fc1 = uv(A0.w, A1.x, A1.y);
    const PV3 Fc2 = uv(A1.z, A1.w, A2.x);
    const PV3 p = uv(A2.y, A2.z, A2.w);

    PV3 tl = fl + cl;
    PV3 ta = fa + ca;
    f32x2 tau;
    if (AX == 0) tau = ta.z;
    else if (AX == 1) tau = ta.y;
    else tau = splat(0.f) - ta.y;

    PV3 R0, R1, R2;
    make_R<AX>(Fc0, Fc1, Fc2, s, c, R0, R1, R2);
    PV3 nl = tl.x * R0 + tl.y * R1 + tl.z * R2;   // R @ tl (columns)
    PV3 na = ta.x * R0 + ta.y * R1 + ta.z * R2 + cross(p, nl);
    cl = nl;
    ca = na;
    return tau;
}

// axis id for dof d: sequence z,y,z,-y,z,y,z -> 0,1,0,2,0,1,0
__device__ __forceinline__ int axid(int d) { return (d & 1) ? ((d == 3) ? 2 : 1) : 0; }

// ---------- main kernel ----------
// r8 (packed dual-row loop-form) + two instruction-count trims:
//  1. prep inlined per block (r6-proven): kills the serialized 1-block prep
//     kernel and its ~2-4 us graph-dispatch latency per iteration.
//  2. fwd parks packed s,c alongside fl/fa (SLOTS 6->8, LDS 30.7->41 KB,
//     still >=3 blocks/CU; occupancy insensitive to blocks/CU since r6):
//     bwd drops its q reloads + 4 transcendentals + range-reduction muls
//     per iteration for 2 ds_read_b64.
__global__ __launch_bounds__(BLK) void rnea_main(
    const float* __restrict__ q_g, const float* __restrict__ qd_g,
    const float* __restrict__ qdd_g,
    const float* __restrict__ rot_fix, const float* __restrict__ trans_fix,
    const float* __restrict__ mass_g, const float* __restrict__ com_g,
    const float* __restrict__ inertia_g, const float* __restrict__ damping_g,
    float* __restrict__ out, int nbatch) {
    __shared__ __align__(16) float sC[CST_TOT];
    __shared__ f32x2 sF[SF_V2];
    const int t = threadIdx.x;
    const int rowA = blockIdx.x * RPB + t;
    const int rowB = rowA + BLK;
    const bool okA = rowA < nbatch;
    const bool okB = rowB < nbatch;
    const int rcA = okA ? rowA : (nbatch - 1);
    const int rcB = okB ? rowB : (nbatch - 1);
    const size_t goA = (size_t)rcA * NDOF;
    const size_t goB = (size_t)rcB * NDOF;

    // inline prep (7 threads; ~40 loads each, L2-hot after first blocks)
    if (t < NDOF) {
        const int d = t;
        float* o = sC + d * CST_STRIDE;
        const float* F = rot_fix + (1 + d) * 9;
#pragma unroll
        for (int j = 0; j < 3; j++)
#pragma unroll
            for (int i = 0; i < 3; i++) o[j * 3 + i] = F[i * 3 + j];  // column-major
#pragma unroll
        for (int i = 0; i < 3; i++) o[9 + i] = trans_fix[(1 + d) * 3 + i];
        const float m = mass_g[1 + d];
        const float c0 = com_g[(1 + d) * 3 + 0];
        const float c1 = com_g[(1 + d) * 3 + 1];
        const float c2 = com_g[(1 + d) * 3 + 2];
        const float* I = inertia_g + (1 + d) * 9;
        o[12] = I[0] + m * (c1 * c1 + c2 * c2);
        o[13] = I[1] - m * c0 * c1;
        o[14] = I[2] - m * c0 * c2;
        o[15] = I[4] + m * (c0 * c0 + c2 * c2);
        o[16] = I[5] - m * c1 * c2;
        o[17] = I[8] + m * (c0 * c0 + c1 * c1);
        o[18] = m;
        o[19] = m * c0;
        o[20] = m * c1;
        o[21] = m * c2;
        o[22] = damping_g[d];
        o[23] = 0.f;
    }
    __syncthreads();

    // ---------------- forward pass: loop over parked links 0..4 ----------------
    PV3 vl{splat(0.f), splat(0.f), splat(0.f)};
    PV3 va = vl, aa = vl;
    PV3 al{splat(0.f), splat(0.f), splat(9.81f)};
    f32x2 qn, qdn, qddn;
    qn.x = q_g[goA];   qn.y = q_g[goB];
    qdn.x = qd_g[goA]; qdn.y = qd_g[goB];
    qddn.x = qdd_g[goA]; qddn.y = qdd_g[goB];
#pragma clang loop unroll(disable)
    for (int d = 0; d < NPARK; ++d) {
        const f32x2 q = qn, qd = qdn, qdd = qddn;
        qn.x = q_g[goA + d + 1];   qn.y = q_g[goB + d + 1];     // prefetch next
        qdn.x = qd_g[goA + d + 1]; qdn.y = qd_g[goB + d + 1];
        qddn.x = qdd_g[goA + d + 1]; qddn.y = qdd_g[goB + d + 1];
        f32x2 s, c;
        s.x = __sinf(q.x); s.y = __sinf(q.y);
        c.x = __cosf(q.x); c.y = __cosf(q.y);
        const float4* C4 = reinterpret_cast<const float4*>(sC) + d * 6;
        const float4 A0 = C4[0], A1 = C4[1], A2 = C4[2], A3 = C4[3], A4 = C4[4], A5 = C4[5];
        PV3 fl, fa;
        switch (axid(d)) {
            case 0: fwd_step<0>(A0, A1, A2, A3, A4, A5, s, c, qd, qdd, vl, va, al, aa, fl, fa); break;
            case 1: fwd_step<1>(A0, A1, A2, A3, A4, A5, s, c, qd, qdd, vl, va, al, aa, fl, fa); break;
            default: fwd_step<2>(A0, A1, A2, A3, A4, A5, s, c, qd, qdd, vl, va, al, aa, fl, fa); break;
        }
        f32x2* r = sF + d * SLOTS * BLK + t;   // [link][slot][thread], ds_write_b64
        r[0 * BLK] = fl.x; r[1 * BLK] = fl.y; r[2 * BLK] = fl.z;
        r[3 * BLK] = fa.x; r[4 * BLK] = fa.y; r[5 * BLK] = fa.z;
        r[6 * BLK] = s;    r[7 * BLK] = c;    // park sin/cos for bwd
    }

    // ---------------- peel: links 5,6 fwd -> immediate bwd in registers ----------
    const f32x2 q5 = qn, qd5 = qdn, qdd5 = qddn;    // prefetched above
    f32x2 q6, qd6, qdd6;
    q6.x = q_g[goA + 6];   q6.y = q_g[goB + 6];
    qd6.x = qd_g[goA + 6]; qd6.y = qd_g[goB + 6];
    qdd6.x = qdd_g[goA + 6]; qdd6.y = qdd_g[goB + 6];
    f32x2 s5, c5, s6, c6;
    s5.x = __sinf(q5.x); s5.y = __sinf(q5.y);
    c5.x = __cosf(q5.x); c5.y = __cosf(q5.y);
    s6.x = __sinf(q6.x); s6.y = __sinf(q6.y);
    c6.x = __cosf(q6.x); c6.y = __cosf(q6.y);
    PV3 cl{splat(0.f), splat(0.f), splat(0.f)}, ca = cl;
    f32x2 tau5, tau6;
    {
        const float4* C5 = reinterpret_cast<const float4*>(sC) + 5 * 6;
        const float4 B0 = C5[0], B1 = C5[1], B2 = C5[2], B3 = C5[3], B4 = C5[4], B5 = C5[5];
        const float4* C6 = reinterpret_cast<const float4*>(sC) + 6 * 6;
        const float4 D0 = C6[0], D1 = C6[1], D2 = C6[2], D3 = C6[3], D4 = C6[4], D5 = C6[5];
        PV3 fl5, fa5, fl6, fa6;
        fwd_step<1>(B0, B1, B2, B3, B4, B5, s5, c5, qd5, qdd5, vl, va, al, aa, fl5, fa5);
        fwd_step<0>(D0, D1, D2, D3, D4, D5, s6, c6, qd6, qdd6, vl, va, al, aa, fl6, fa6);
        tau6 = bwd_core<0>(D0, D1, D2, s6, c6, fl6, fa6, cl, ca) + splat(D5.z) * qd6;
        tau5 = bwd_core<1>(B0, B1, B2, s5, c5, fl5, fa5, cl, ca) + splat(B5.z) * qd5;
        // damp lives at float offset 22 == component .z of float4 #5
    }

    // ---------------- backward pass: loop over parked links 4..0 ----------------
    // same-thread LDS reuse only -> no barrier; finished packed tau overwrites
    // the just-consumed fl.x slot so all global stores issue together below.
#pragma clang loop unroll(disable)
    for (int d = NPARK - 1; d >= 0; --d) {
        f32x2 qd;
        qd.x = qd_g[goA + d]; qd.y = qd_g[goB + d];   // L1-hot reload (damping)
        const float4* C4 = reinterpret_cast<const float4*>(sC) + d * 6;
        const float4 A0 = C4[0], A1 = C4[1], A2 = C4[2];
        const float damp = sC[d * CST_STRIDE + 22];
        f32x2* r = sF + d * SLOTS * BLK + t;
        const PV3 fl{r[0 * BLK], r[1 * BLK], r[2 * BLK]};
        const PV3 fa{r[3 * BLK], r[4 * BLK], r[5 * BLK]};
        const f32x2 s = r[6 * BLK];
        const f32x2 c = r[7 * BLK];
        f32x2 tau;
        switch (axid(d)) {
            case 0: tau = bwd_core<0>(A0, A1, A2, s, c, fl, fa, cl, ca); break;
            case 1: tau = bwd_core<1>(A0, A1, A2, s, c, fl, fa, cl, ca); break;
            default: tau = bwd_core<2>(A0, A1, A2, s, c, fl, fa, cl, ca); break;
        }
        r[0] = tau + splat(damp) * qd;   // park finished packed tau
    }

    // ---------------- stores: all back-to-back (write-combine friendly) ---------
    if (okA) {
#pragma unroll
        for (int d = 0; d < NPARK; ++d) out[goA + d] = sF[d * SLOTS * BLK + t].x;
        out[goA + 5] = tau5.x;
        out[goA + 6] = tau6.x;
    }
    if (okB) {
#pragma unroll
        for (int d = 0; d < NPARK; ++d) out[goB + d] = sF[d * SLOTS * BLK + t].y;
        out[goB + 5] = tau5.y;
        out[goB + 6] = tau6.y;
    }
}

extern "C" void kernel_launch(void* const* d_in, const int* in_sizes, int n_in,
                              void* d_out, int out_size, void* d_ws, size_t ws_size,
                              hipStream_t stream) {
    const float* q = (const float*)d_in[0];
    const float* qd = (const float*)d_in[1];
    const float* qdd = (const float*)d_in[2];
    const float* rot_fix = (const float*)d_in[3];
    const float* trans_fix = (const float*)d_in[4];
    // d_in[5] = joint_axes: compile-time constant in the reference (z,y,z,-y,z,y,z)
    const float* mass = (const float*)d_in[6];
    const float* com = (const float*)d_in[7];
    const float* inertia = (const float*)d_in[8];
    const float* damping = (const float*)d_in[9];
    float* out = (float*)d_out;

    const int n_elem = in_sizes[0];  // B * 7
    const int B = n_elem / NDOF;
    const int grid = (B + RPB - 1) / RPB;

    rnea_main<<<grid, BLK, 0, stream>>>(q, qd, qdd, rot_fix, trans_fix, mass, com,
                                        inertia, damping, out, B);
}

// Round 10
// 120.021 us; speedup vs baseline: 1.0066x; 1.0066x over previous
//
#include <hip/hip_runtime.h>

#define NDOF 7
#define NPARK 5                     // links 0..4 parked in LDS; 5,6 fused in regs
#define BLK 128                     // threads per block (2 waves)
#define RPB 256                     // rows per block (2 rows per thread: A, B)
#define CST_STRIDE 24               // floats per dof block (= 6 float4)
#define CST_TOT (NDOF * CST_STRIDE) // 168
#define SF_V2 (NPARK * 6 * BLK)     // f32x2 elements: 5*6*128*8B = 30720 B

// ---------- packed pair type: lane .x = row A, lane .y = row B ----------
// <2 x float> IR -> v_pk_fma_f32/v_pk_add_f32/v_pk_mul_f32 on gfx950:
// one VALU instruction per 2-row operation.  r8 measured: this was the one
// change that broke the r2-r7 VALU-issue floor (total 130 -> 118 us).
// r9's "trims" (inline prep, parked sin/cos) regressed to 120.8 -> reverted.
typedef float f32x2 __attribute__((ext_vector_type(2)));

__device__ __forceinline__ f32x2 splat(float v) { f32x2 r; r.x = v; r.y = v; return r; }

struct PV3 { f32x2 x, y, z; };
__device__ __forceinline__ PV3 operator+(PV3 a, PV3 b) { return {a.x + b.x, a.y + b.y, a.z + b.z}; }
__device__ __forceinline__ PV3 operator-(PV3 a, PV3 b) { return {a.x - b.x, a.y - b.y, a.z - b.z}; }
__device__ __forceinline__ PV3 operator*(f32x2 s, PV3 a) { return {s * a.x, s * a.y, s * a.z}; }
__device__ __forceinline__ PV3 cross(PV3 a, PV3 b) {
    return {a.y * b.z - a.z * b.y, a.z * b.x - a.x * b.z, a.x * b.y - a.y * b.x};
}
__device__ __forceinline__ f32x2 dot(PV3 a, PV3 b) { return a.x * b.x + a.y * b.y + a.z * b.z; }
__device__ __forceinline__ PV3 uv(float x, float y, float z) { return {splat(x), splat(y), splat(z)}; }

// ---------- prep: pack per-dof constants into d_ws ----------
// per dof d (24 floats): [0:9) F columns (column-major), [9:12) p,
// [12:18) Io6=I00,I01,I02,I11,I12,I22, [18] m, [19:22) mc, [22] damp, [23] pad
// Separate 1-block kernel (NOT inlined): r9 showed per-block inline prep
// costs ~1-2 us (40 divergent loads + barrier at every block head with only
// 2 waves to overlap them), while this kernel's dispatch hides in graph slack.
__global__ void rnea_prep(const float* __restrict__ rot_fix,
                          const float* __restrict__ trans_fix,
                          const float* __restrict__ mass_g,
                          const float* __restrict__ com_g,
                          const float* __restrict__ inertia_g,
                          const float* __restrict__ damping_g,
                          float* __restrict__ cst) {
    const int d = threadIdx.x;
    if (d >= NDOF) return;
    float* o = cst + d * CST_STRIDE;
    const float* F = rot_fix + (1 + d) * 9;
#pragma unroll
    for (int j = 0; j < 3; j++)
#pragma unroll
        for (int i = 0; i < 3; i++) o[j * 3 + i] = F[i * 3 + j];  // column-major
#pragma unroll
    for (int i = 0; i < 3; i++) o[9 + i] = trans_fix[(1 + d) * 3 + i];
    const float m = mass_g[1 + d];
    const float c0 = com_g[(1 + d) * 3 + 0];
    const float c1 = com_g[(1 + d) * 3 + 1];
    const float c2 = com_g[(1 + d) * 3 + 2];
    const float* I = inertia_g + (1 + d) * 9;
    o[12] = I[0] + m * (c1 * c1 + c2 * c2);
    o[13] = I[1] - m * c0 * c1;
    o[14] = I[2] - m * c0 * c2;
    o[15] = I[4] + m * (c0 * c0 + c2 * c2);
    o[16] = I[5] - m * c1 * c2;
    o[17] = I[8] + m * (c0 * c0 + c1 * c1);
    o[18] = m;
    o[19] = m * c0;
    o[20] = m * c1;
    o[21] = m * c2;
    o[22] = damping_g[d];
    o[23] = 0.f;
}

// AX: 0 = +z, 1 = +y, 2 = -y   (joint_axes is a literal in the reference)
template <int AX>
__device__ __forceinline__ void make_R(PV3 Fc0, PV3 Fc1, PV3 Fc2, f32x2 s, f32x2 c,
                                       PV3& R0, PV3& R1, PV3& R2) {
    if (AX == 0) {          // Rq_z cols: (c,s,0), (-s,c,0), (0,0,1)
        R0 = c * Fc0 + s * Fc1;
        R1 = c * Fc1 - s * Fc0;
        R2 = Fc2;
    } else if (AX == 1) {   // Rq_y cols: (c,0,-s), (0,1,0), (s,0,c)
        R0 = c * Fc0 - s * Fc2;
        R1 = Fc1;
        R2 = s * Fc0 + c * Fc2;
    } else {                // Rq_-y cols: (c,0,s), (0,1,0), (-s,0,c)
        R0 = c * Fc0 + s * Fc2;
        R1 = Fc1;
        R2 = c * Fc2 - s * Fc0;
    }
}

// fwd: both rows in one packed pass; constants wave-uniform (broadcast).
template <int AX>
__device__ __forceinline__ void fwd_step(float4 A0, float4 A1, float4 A2, float4 A3,
                                         float4 A4, float4 A5, f32x2 s, f32x2 c,
                                         f32x2 qd, f32x2 qdd, PV3& vl, PV3& va, PV3& al,
                                         PV3& aa, PV3& fl, PV3& fa) {
    const PV3 Fc0 = uv(A0.x, A0.y, A0.z);
    const PV3 Fc1 = uv(A0.w, A1.x, A1.y);
    const PV3 Fc2 = uv(A1.z, A1.w, A2.x);
    const PV3 p = uv(A2.y, A2.z, A2.w);
    const f32x2 I00 = splat(A3.x), I01 = splat(A3.y), I02 = splat(A3.z);
    const f32x2 I11 = splat(A3.w), I12 = splat(A4.x), I22 = splat(A4.y);
    const f32x2 m = splat(A4.z);
    const PV3 mc = uv(A4.w, A5.x, A5.y);

    PV3 R0, R1, R2;
    make_R<AX>(Fc0, Fc1, Fc2, s, c, R0, R1, R2);

    // Rt(vl) + cross(-Rt p, Rt va) == Rt(vl + va x p)
    PV3 w1 = vl + cross(va, p);
    PV3 w2 = al + cross(aa, p);
    PV3 nvl{dot(R0, w1), dot(R1, w1), dot(R2, w1)};
    PV3 nva{dot(R0, va), dot(R1, va), dot(R2, va)};
    PV3 nal{dot(R0, w2), dot(R1, w2), dot(R2, w2)};
    PV3 naa{dot(R0, aa), dot(R1, aa), dot(R2, aa)};

    if (AX == 0) {          // jv=(0,0,qd): cross(v,jv)=(v.y*qd,-v.x*qd,0)
        va = {nva.x, nva.y, nva.z + qd};
        aa = {naa.x + va.y * qd, naa.y - va.x * qd, naa.z + qdd};
        vl = nvl;
        al = {nal.x + vl.y * qd, nal.y - vl.x * qd, nal.z};
    } else if (AX == 1) {   // jv=(0,qd,0): cross(v,jv)=(-v.z*qd,0,v.x*qd)
        va = {nva.x, nva.y + qd, nva.z};
        aa = {naa.x - va.z * qd, naa.y + qdd, naa.z + va.x * qd};
        vl = nvl;
        al = {nal.x - vl.z * qd, nal.y, nal.z + vl.x * qd};
    } else {                // jv=(0,-qd,0): cross(v,jv)=(v.z*qd,0,-v.x*qd)
        va = {nva.x, nva.y - qd, nva.z};
        aa = {naa.x + va.z * qd, naa.y - qdd, naa.z - va.x * qd};
        vl = nvl;
        al = {nal.x + vl.z * qd, nal.y, nal.z - vl.x * qd};
    }

    PV3 Ial = m * al + cross(aa, mc);
    PV3 Iaa = PV3{I00 * aa.x + I01 * aa.y + I02 * aa.z,
                  I01 * aa.x + I11 * aa.y + I12 * aa.z,
                  I02 * aa.x + I12 * aa.y + I22 * aa.z} + cross(mc, al);
    PV3 Ivl = m * vl + cross(va, mc);
    PV3 Iva = PV3{I00 * va.x + I01 * va.y + I02 * va.z,
                  I01 * va.x + I11 * va.y + I12 * va.z,
                  I02 * va.x + I12 * va.y + I22 * va.z} + cross(mc, vl);
    fl = Ial + cross(va, Ivl);
    fa = Iaa + cross(va, Iva) + cross(vl, Ivl);
}

// bwd: both rows packed; updates carry, returns packed tau.
template <int AX>
__device__ __forceinline__ f32x2 bwd_core(float4 A0, float4 A1, float4 A2,
                                          f32x2 s, f32x2 c,
                                          PV3 fl, PV3 fa, PV3& cl, PV3& ca) {
    const PV3 Fc0 = uv(A0.x, A0.y, A0.z);
    const PV3 Fc1 = uv(A0.w, A1.x, A1.y);
    const PV3 Fc2 = uv(A1.z, A1.w, A2.x);
    const PV3 p = uv(A2.y, A2.z, A2.w);

    PV3 tl = fl + cl;
    PV3 ta = fa + ca;
    f32x2 tau;
    if (AX == 0) tau = ta.z;
    else if (AX == 1) tau = ta.y;
    else tau = splat(0.f) - ta.y;

    PV3 R0, R1, R2;
    make_R<AX>(Fc0, Fc1, Fc2, s, c, R0, R1, R2);
    PV3 nl = tl.x * R0 + tl.y * R1 + tl.z * R2;   // R @ tl (columns)
    PV3 na = ta.x * R0 + ta.y * R1 + ta.z * R2 + cross(p, nl);
    cl = nl;
    ca = na;
    return tau;
}

// axis id for dof d: sequence z,y,z,-y,z,y,z -> 0,1,0,2,0,1,0
__device__ __forceinline__ int axid(int d) { return (d & 1) ? ((d == 3) ? 2 : 1) : 0; }

// ---------- main kernel ----------
// PACKED dual-row loop-form O(n) RNEA — the r8 best-measured configuration
// (117.8 us total), restored verbatim after r9's trims regressed.
// Structure: loop form keeps the body I$-resident (r5: front-end limit);
// dual-row + v_pk_* halves issued VALU per row-pair (r8: the floor-breaker);
// LDS parks links 0..4 wrenches, links 5,6 fwd->bwd fused in regs (r6);
// all global stores issue back-to-back at the end (r6: WRITE_SIZE 14.3 MB).
__global__ __launch_bounds__(BLK) void rnea_main(
    const float* __restrict__ q_g, const float* __restrict__ qd_g,
    const float* __restrict__ qdd_g, const float* __restrict__ cst,
    float* __restrict__ out, int nbatch) {
    __shared__ __align__(16) float sC[CST_TOT];
    __shared__ f32x2 sF[SF_V2];
    const int t = threadIdx.x;
    const int rowA = blockIdx.x * RPB + t;
    const int rowB = rowA + BLK;
    const bool okA = rowA < nbatch;
    const bool okB = rowB < nbatch;
    const int rcA = okA ? rowA : (nbatch - 1);
    const int rcB = okB ? rowB : (nbatch - 1);
    const size_t goA = (size_t)rcA * NDOF;
    const size_t goB = (size_t)rcB * NDOF;

    if (t < CST_TOT / 4)   // 42 float4 = one coalesced burst
        reinterpret_cast<float4*>(sC)[t] = reinterpret_cast<const float4*>(cst)[t];
    __syncthreads();

    // ---------------- forward pass: loop over parked links 0..4 ----------------
    PV3 vl{splat(0.f), splat(0.f), splat(0.f)};
    PV3 va = vl, aa = vl;
    PV3 al{splat(0.f), splat(0.f), splat(9.81f)};
    f32x2 qn, qdn, qddn;
    qn.x = q_g[goA];   qn.y = q_g[goB];
    qdn.x = qd_g[goA]; qdn.y = qd_g[goB];
    qddn.x = qdd_g[goA]; qddn.y = qdd_g[goB];
#pragma clang loop unroll(disable)
    for (int d = 0; d < NPARK; ++d) {
        const f32x2 q = qn, qd = qdn, qdd = qddn;
        qn.x = q_g[goA + d + 1];   qn.y = q_g[goB + d + 1];     // prefetch next
        qdn.x = qd_g[goA + d + 1]; qdn.y = qd_g[goB + d + 1];
        qddn.x = qdd_g[goA + d + 1]; qddn.y = qdd_g[goB + d + 1];
        f32x2 s, c;
        s.x = __sinf(q.x); s.y = __sinf(q.y);
        c.x = __cosf(q.x); c.y = __cosf(q.y);
        const float4* C4 = reinterpret_cast<const float4*>(sC) + d * 6;
        const float4 A0 = C4[0], A1 = C4[1], A2 = C4[2], A3 = C4[3], A4 = C4[4], A5 = C4[5];
        PV3 fl, fa;
        switch (axid(d)) {
            case 0: fwd_step<0>(A0, A1, A2, A3, A4, A5, s, c, qd, qdd, vl, va, al, aa, fl, fa); break;
            case 1: fwd_step<1>(A0, A1, A2, A3, A4, A5, s, c, qd, qdd, vl, va, al, aa, fl, fa); break;
            default: fwd_step<2>(A0, A1, A2, A3, A4, A5, s, c, qd, qdd, vl, va, al, aa, fl, fa); break;
        }
        f32x2* r = sF + d * 6 * BLK + t;   // [link][comp][thread], ds_write_b64
        r[0 * BLK] = fl.x; r[1 * BLK] = fl.y; r[2 * BLK] = fl.z;
        r[3 * BLK] = fa.x; r[4 * BLK] = fa.y; r[5 * BLK] = fa.z;
    }

    // ---------------- peel: links 5,6 fwd -> immediate bwd in registers ----------
    const f32x2 q5 = qn, qd5 = qdn, qdd5 = qddn;    // prefetched above
    f32x2 q6, qd6, qdd6;
    q6.x = q_g[goA + 6];   q6.y = q_g[goB + 6];
    qd6.x = qd_g[goA + 6]; qd6.y = qd_g[goB + 6];
    qdd6.x = qdd_g[goA + 6]; qdd6.y = qdd_g[goB + 6];
    f32x2 s5, c5, s6, c6;
    s5.x = __sinf(q5.x); s5.y = __sinf(q5.y);
    c5.x = __cosf(q5.x); c5.y = __cosf(q5.y);
    s6.x = __sinf(q6.x); s6.y = __sinf(q6.y);
    c6.x = __cosf(q6.x); c6.y = __cosf(q6.y);
    PV3 cl{splat(0.f), splat(0.f), splat(0.f)}, ca = cl;
    f32x2 tau5, tau6;
    {
        const float4* C5 = reinterpret_cast<const float4*>(sC) + 5 * 6;
        const float4 B0 = C5[0], B1 = C5[1], B2 = C5[2], B3 = C5[3], B4 = C5[4], B5 = C5[5];
        const float4* C6 = reinterpret_cast<const float4*>(sC) + 6 * 6;
        const float4 D0 = C6[0], D1 = C6[1], D2 = C6[2], D3 = C6[3], D4 = C6[4], D5 = C6[5];
        PV3 fl5, fa5, fl6, fa6;
        fwd_step<1>(B0, B1, B2, B3, B4, B5, s5, c5, qd5, qdd5, vl, va, al, aa, fl5, fa5);
        fwd_step<0>(D0, D1, D2, D3, D4, D5, s6, c6, qd6, qdd6, vl, va, al, aa, fl6, fa6);
        tau6 = bwd_core<0>(D0, D1, D2, s6, c6, fl6, fa6, cl, ca) + splat(D5.z) * qd6;
        tau5 = bwd_core<1>(B0, B1, B2, s5, c5, fl5, fa5, cl, ca) + splat(B5.z) * qd5;
        // damp lives at float offset 22 == component .z of float4 #5
    }

    // ---------------- backward pass: loop over parked links 4..0 ----------------
    // same-thread LDS reuse only -> no barrier; finished packed tau overwrites
    // the just-consumed fl.x slot so all global stores issue together below.
#pragma clang loop unroll(disable)
    for (int d = NPARK - 1; d >= 0; --d) {
        f32x2 q, qd;
        q.x = q_g[goA + d];  q.y = q_g[goB + d];    // L1-hot reload
        qd.x = qd_g[goA + d]; qd.y = qd_g[goB + d];
        f32x2 s, c;
        s.x = __sinf(q.x); s.y = __sinf(q.y);
        c.x = __cosf(q.x); c.y = __cosf(q.y);
        const float4* C4 = reinterpret_cast<const float4*>(sC) + d * 6;
        const float4 A0 = C4[0], A1 = C4[1], A2 = C4[2];
        const float damp = sC[d * CST_STRIDE + 22];
        f32x2* r = sF + d * 6 * BLK + t;
        const PV3 fl{r[0 * BLK], r[1 * BLK], r[2 * BLK]};
        const PV3 fa{r[3 * BLK], r[4 * BLK], r[5 * BLK]};
        f32x2 tau;
        switch (axid(d)) {
            case 0: tau = bwd_core<0>(A0, A1, A2, s, c, fl, fa, cl, ca); break;
            case 1: tau = bwd_core<1>(A0, A1, A2, s, c, fl, fa, cl, ca); break;
            default: tau = bwd_core<2>(A0, A1, A2, s, c, fl, fa, cl, ca); break;
        }
        r[0] = tau + splat(damp) * qd;   // park finished packed tau
    }

    // ---------------- stores: all back-to-back (write-combine friendly) ---------
    if (okA) {
#pragma unroll
        for (int d = 0; d < NPARK; ++d) out[goA + d] = sF[d * 6 * BLK + t].x;
        out[goA + 5] = tau5.x;
        out[goA + 6] = tau6.x;
    }
    if (okB) {
#pragma unroll
        for (int d = 0; d < NPARK; ++d) out[goB + d] = sF[d * 6 * BLK + t].y;
        out[goB + 5] = tau5.y;
        out[goB + 6] = tau6.y;
    }
}

extern "C" void kernel_launch(void* const* d_in, const int* in_sizes, int n_in,
                              void* d_out, int out_size, void* d_ws, size_t ws_size,
                              hipStream_t stream) {
    const float* q = (const float*)d_in[0];
    const float* qd = (const float*)d_in[1];
    const float* qdd = (const float*)d_in[2];
    const float* rot_fix = (const float*)d_in[3];
    const float* trans_fix = (const float*)d_in[4];
    // d_in[5] = joint_axes: compile-time constant in the reference (z,y,z,-y,z,y,z)
    const float* mass = (const float*)d_in[6];
    const float* com = (const float*)d_in[7];
    const float* inertia = (const float*)d_in[8];
    const float* damping = (const float*)d_in[9];
    float* out = (float*)d_out;
    float* cst = (float*)d_ws;  // 7*24*4 = 672 B

    const int n_elem = in_sizes[0];  // B * 7
    const int B = n_elem / NDOF;
    const int grid = (B + RPB - 1) / RPB;

    rnea_prep<<<1, 64, 0, stream>>>(rot_fix, trans_fix, mass, com, inertia, damping, cst);
    rnea_main<<<grid, BLK, 0, stream>>>(q, qd, qdd, cst, out, B);
}